// Round 3
// baseline (4710.086 us; speedup 1.0000x reference)
//
#include <hip/hip_runtime.h>
#include <math.h>

#define TPB 256

// Fused conv3d(3x3x3,pad1) -> cubic KAN spline + SiLU -> BN(eval) -> maxpool 2x2x2.
// Block = (n, cout-group, spatial tile of PDT x PHT x PWT pooled voxels).
// Per cin: staged halo'd input slab in LDS (boundary zeroed at staging => branch-free
// compute), register-prefetch of cin+1's slab overlaps the 216*G FMAs of cin.
// LDS swizzle: phys wx = logical wx + ((hy>>1)&1) on even pitch -> stride-2 lane
// reads spread over both bank parities (2-way, ~free).
template <int CIN, int G, int PDT, int PHT, int PWT>
__global__ __launch_bounds__(TPB, 2) void spline_block_kernel(
    const float* __restrict__ x,    // [N, CIN, D, H, W]
    const float* __restrict__ cw,   // [Cout, CIN, 27]
    const float* __restrict__ cb,   // [Cout]
    const float* __restrict__ knots,// [10]
    const float* __restrict__ sw,   // [Cout, 10]
    const float* __restrict__ w1,   // [Cout]
    const float* __restrict__ w2,   // [Cout]
    const float* __restrict__ g,    // [Cout]
    const float* __restrict__ beta, // [Cout]
    float* __restrict__ out,        // [N, Cout, PD, PH, PW]
    int N, int Cout, int D, int H, int W,
    int ntiles, int nthw, int ntw)  // spatial tile counts: total, nth*ntw, ntw
{
    constexpr int ID    = 2 * PDT + 2;
    constexpr int IH    = 2 * PHT + 2;
    constexpr int IW    = 2 * PWT + 2;
    constexpr int PITCH = IW + 2;              // even pitch; +swizzle bit fits
    constexpr int PHYS  = ID * IH * PITCH;
    constexpr int NST   = (PHYS + TPB - 1) / TPB;
    static_assert(NST <= 32, "mask fits u32");

    __shared__ float tile[PHYS];
    __shared__ float wlds[CIN * G * 28];       // [ci][gg][27 pad 28] (16B rows)

    const int PD = D >> 1, PH = H >> 1, PW = W >> 1;
    const int groups = Cout / G;
    const int tid = threadIdx.x;

    const int bx      = blockIdx.x;
    const int tile_id = bx % ntiles;
    const int t1      = bx / ntiles;
    const int grp     = t1 % groups;
    const int n       = t1 / groups;
    const int c0      = grp * G;

    const int td  = tile_id / nthw;
    const int rem = tile_id % nthw;
    const int th_ = rem / ntw;
    const int tw_ = rem % ntw;

    // stage conv weights (barrier below covers this too)
    for (int i = tid; i < CIN * G * 27; i += TPB) {
        const int t  = i % 27;
        const int cg = i / 27;
        const int gg = cg % G;
        const int ci = cg / G;
        wlds[cg * 28 + t] = cw[((c0 + gg) * CIN + ci) * 27 + t];
    }

    // thread's pooled voxel within the tile
    const int pwl = tid % PWT;
    const int phl = (tid / PWT) % PHT;
    const int pdl = tid / (PWT * PHT);

    const int pd0 = td * PDT, ph0 = th_ * PHT, pw0 = tw_ * PWT;
    const int d0 = 2 * pd0 - 1, h0 = 2 * ph0 - 1, w0 = 2 * pw0 - 1;

    // precompute staging offsets + validity mask (shared across all cin)
    int offg[NST];
    unsigned vmask = 0;
#pragma unroll
    for (int k = 0; k < NST; k++) {
        const int p   = tid + TPB * k;
        const int row = p / PITCH;
        const int wxs = p % PITCH;
        const int dz  = row / IH;
        const int hy  = row % IH;
        const int wx  = wxs - ((hy >> 1) & 1);     // undo swizzle -> logical
        const int dd = d0 + dz, hh = h0 + hy, ww = w0 + wx;
        const bool ok = (p < PHYS) & (wx >= 0) & (wx < IW) &
                        ((unsigned)dd < (unsigned)D) &
                        ((unsigned)hh < (unsigned)H) &
                        ((unsigned)ww < (unsigned)W);
        offg[k] = ok ? (dd * H + hh) * W + ww : 0;
        vmask |= (unsigned)ok << k;
    }

    const size_t chstride = (size_t)D * H * W;
    const float* xn = x + (size_t)n * CIN * chstride;

    float acc[G][8];
#pragma unroll
    for (int gg = 0; gg < G; gg++) {
        const float bias = cb[c0 + gg];
#pragma unroll
        for (int i = 0; i < 8; i++) acc[gg][i] = bias;
    }

    // stage cin 0
    {
        float pf[NST];
#pragma unroll
        for (int k = 0; k < NST; k++) pf[k] = xn[offg[k]];
#pragma unroll
        for (int k = 0; k < NST; k++) {
            const int p = tid + TPB * k;
            if ((PHYS % TPB) == 0 || k < NST - 1 || p < PHYS)
                tile[p] = ((vmask >> k) & 1) ? pf[k] : 0.0f;
        }
    }
    __syncthreads();

#pragma unroll 1
    for (int ci = 0; ci < CIN; ci++) {
        // issue prefetch of next cin's slab (latency covered by FMAs below)
        float pfn[NST];
        if (ci + 1 < CIN) {
            const float* xc = xn + (size_t)(ci + 1) * chstride;
#pragma unroll
            for (int k = 0; k < NST; k++) pfn[k] = xc[offg[k]];
        }

        // read this thread's 4x4x4 window from LDS (branch-free)
        float r[64];
#pragma unroll
        for (int dz = 0; dz < 4; dz++)
#pragma unroll
        for (int dy = 0; dy < 4; dy++) {
            const int hy = 2 * phl + dy;
            const float* bp =
                &tile[((2 * pdl + dz) * IH + hy) * PITCH + 2 * pwl + ((hy >> 1) & 1)];
#pragma unroll
            for (int dx = 0; dx < 4; dx++)
                r[(dz * 4 + dy) * 4 + dx] = bp[dx];
        }

#pragma unroll
        for (int gg = 0; gg < G; gg++) {
            const float4* w4p = (const float4*)&wlds[(ci * G + gg) * 28];
#pragma unroll
            for (int ch = 0; ch < 7; ch++) {
                const float4 wv = w4p[ch];
#pragma unroll
                for (int j = 0; j < 4; j++) {
                    const int tap = ch * 4 + j;
                    if (tap < 27) {
                        const float wvj = (j == 0) ? wv.x : (j == 1) ? wv.y
                                        : (j == 2) ? wv.z : wv.w;
                        const int kd = tap / 9, kh = (tap % 9) / 3, kw = tap % 3;
#pragma unroll
                        for (int od = 0; od < 2; od++)
#pragma unroll
                        for (int oh = 0; oh < 2; oh++)
#pragma unroll
                        for (int ow = 0; ow < 2; ow++)
                            acc[gg][(od * 2 + oh) * 2 + ow] =
                                fmaf(wvj,
                                     r[((od + kd) * 4 + (oh + kh)) * 4 + (ow + kw)],
                                     acc[gg][(od * 2 + oh) * 2 + ow]);
                    }
                }
            }
        }

        if (ci + 1 < CIN) {
            __syncthreads();   // everyone done reading tile[ci]
#pragma unroll
            for (int k = 0; k < NST; k++) {
                const int p = tid + TPB * k;
                if ((PHYS % TPB) == 0 || k < NST - 1 || p < PHYS)
                    tile[p] = ((vmask >> k) & 1) ? pfn[k] : 0.0f;
            }
            __syncthreads();
        }
    }

    // spline + SiLU + BN affine + maxpool epilogue
    float kn[10];
#pragma unroll
    for (int k = 0; k < 10; k++) kn[k] = knots[k];

    const int pdg = pd0 + pdl, phg = ph0 + phl, pwg = pw0 + pwl;
#pragma unroll
    for (int gg = 0; gg < G; gg++) {
        const int c = c0 + gg;
        float sc[10];
#pragma unroll
        for (int k = 0; k < 10; k++) sc[k] = sw[c * 10 + k];
        const float W1 = w1[c], W2 = w2[c];
        const float scale = g[c] * rsqrtf(1.0f + 1e-5f);
        const float bb = beta[c];

        float m = -INFINITY;
#pragma unroll
        for (int i = 0; i < 8; i++) {
            const float y = acc[gg][i];
            float sp = 0.0f;
#pragma unroll
            for (int k = 0; k < 10; k++) {
                const float tt = fmaxf(y - kn[k], 0.0f);
                sp = fmaf(tt * tt * tt, sc[k], sp);
            }
            const float silu = y / (1.0f + __expf(-y));
            const float o = fmaf(W1 * sp + W2 * silu, scale, bb);
            m = fmaxf(m, o);
        }
        out[((size_t)(n * Cout + c) * PD + pdg) * PH * PW + phg * PW + pwg] = m;
    }
}

// Global average pool: one wave per (n,c); S = spatial size
__global__ __launch_bounds__(64) void mean_kernel(
    const float* __restrict__ h, float* __restrict__ out, int S)
{
    const int nc = blockIdx.x;
    const int lane = threadIdx.x;
    const float* p = h + (size_t)nc * S;
    float s = 0.0f;
    for (int i = lane; i < S; i += 64) s += p[i];
#pragma unroll
    for (int off = 32; off > 0; off >>= 1) s += __shfl_down(s, off, 64);
    if (lane == 0) out[nc] = s / (float)S;
}

// fc1(128->256)+ReLU then fc2(256->2), batch 2. One block of 256 threads.
__global__ __launch_bounds__(TPB) void fc_kernel(
    const float* __restrict__ pooled,
    const float* __restrict__ w1, const float* __restrict__ b1,
    const float* __restrict__ w2, const float* __restrict__ b2,
    float* __restrict__ out)
{
    __shared__ float hbuf[2][TPB];
    const int j = threadIdx.x;
#pragma unroll
    for (int nn = 0; nn < 2; nn++) {
        float s = b1[j];
        for (int k = 0; k < 128; k++)
            s = fmaf(pooled[nn * 128 + k], w1[j * 128 + k], s);
        hbuf[nn][j] = fmaxf(s, 0.0f);
    }
    __syncthreads();
    const int wid = j >> 6, lane = j & 63;
    const int nn = wid >> 1, oo = wid & 1;
    float s = 0.0f;
    for (int k = lane; k < 256; k += 64) s += hbuf[nn][k] * w2[oo * 256 + k];
#pragma unroll
    for (int off = 32; off > 0; off >>= 1) s += __shfl_down(s, off, 64);
    if (lane == 0) out[nn * 2 + oo] = s + b2[oo];
}

extern "C" void kernel_launch(void* const* d_in, const int* in_sizes, int n_in,
                              void* d_out, int out_size, void* d_ws, size_t ws_size,
                              hipStream_t stream) {
    const float* x      = (const float*)d_in[0];
    const float* c1_w   = (const float*)d_in[1];
    const float* c1_b   = (const float*)d_in[2];
    const float* c1_kn  = (const float*)d_in[3];
    const float* c1_sw  = (const float*)d_in[4];
    const float* c1_w1  = (const float*)d_in[5];
    const float* c1_w2  = (const float*)d_in[6];
    const float* bn1_g  = (const float*)d_in[7];
    const float* bn1_b  = (const float*)d_in[8];
    const float* c2_w   = (const float*)d_in[9];
    const float* c2_b   = (const float*)d_in[10];
    const float* c2_kn  = (const float*)d_in[11];
    const float* c2_sw  = (const float*)d_in[12];
    const float* c2_w1  = (const float*)d_in[13];
    const float* c2_w2  = (const float*)d_in[14];
    const float* bn2_g  = (const float*)d_in[15];
    const float* bn2_b  = (const float*)d_in[16];
    const float* c3_w   = (const float*)d_in[17];
    const float* c3_b   = (const float*)d_in[18];
    const float* c3_kn  = (const float*)d_in[19];
    const float* c3_sw  = (const float*)d_in[20];
    const float* c3_w1  = (const float*)d_in[21];
    const float* c3_w2  = (const float*)d_in[22];
    const float* bn3_g  = (const float*)d_in[23];
    const float* bn3_b  = (const float*)d_in[24];
    const float* fc1_w  = (const float*)d_in[25];
    const float* fc1_b  = (const float*)d_in[26];
    const float* fc2_w  = (const float*)d_in[27];
    const float* fc2_b  = (const float*)d_in[28];

    float* ws = (float*)d_ws;
    float* h1     = ws;                  // 2*32*32^3 = 2097152 floats
    float* h2     = h1 + 2097152;        // 2*64*16^3 =  524288 floats
    float* h3     = h2 + 524288;         // 2*128*8^3 =  131072 floats
    float* pooled = h3 + 131072;         // 2*128

    dim3 blk(TPB);
    // L1: (2,1,64^3)->(2,32,32^3). G=4, tile 1x16x16, tiles=32*2*2=128.
    // grid = 2 * (32/4) * 128 = 2048
    spline_block_kernel<1, 4, 1, 16, 16><<<dim3(2048), blk, 0, stream>>>(
        x, c1_w, c1_b, c1_kn, c1_sw, c1_w1, c1_w2, bn1_g, bn1_b, h1,
        2, 32, 64, 64, 64, 128, 4, 2);
    // L2: (2,32,32^3)->(2,64,16^3). G=4, tile 1x16x16, tiles=16.
    // grid = 2 * (64/4) * 16 = 512
    spline_block_kernel<32, 4, 1, 16, 16><<<dim3(512), blk, 0, stream>>>(
        h1, c2_w, c2_b, c2_kn, c2_sw, c2_w1, c2_w2, bn2_g, bn2_b, h2,
        2, 64, 32, 32, 32, 16, 1, 1);
    // L3: (2,64,16^3)->(2,128,8^3). G=2, tile 4x8x8, tiles=2.
    // grid = 2 * (128/2) * 2 = 256
    spline_block_kernel<64, 2, 4, 8, 8><<<dim3(256), blk, 0, stream>>>(
        h2, c3_w, c3_b, c3_kn, c3_sw, c3_w1, c3_w2, bn3_g, bn3_b, h3,
        2, 128, 16, 16, 16, 2, 1, 1);
    // Global mean pool: 256 (n,c) pairs, 512 voxels each
    mean_kernel<<<dim3(256), dim3(64), 0, stream>>>(h3, pooled, 512);
    // FC head
    fc_kernel<<<dim3(1), blk, 0, stream>>>(pooled, fc1_w, fc1_b, fc2_w, fc2_b,
                                           (float*)d_out);
}

// Round 4
// 513.305 us; speedup vs baseline: 9.1760x; 9.1760x over previous
//
#include <hip/hip_runtime.h>
#include <math.h>

// Fused conv3d(3x3x3,pad1) -> cubic KAN spline + SiLU -> BN(eval) -> maxpool 2x2x2.
// Block = (n, cout-group, spatial tile). Input slab staged per-cin into LDS via
// global_load_lds (async DMA, zero VGPR cost), double-buffered; borders pre-zeroed
// once so compute is branch-free. Each thread: 4x4x4 window -> 2x2x2 conv outputs
// for G couts -> spline/SiLU/BN/maxpool epilogue.

#define GLOBAL_AS __attribute__((address_space(1)))
#define LDS_AS    __attribute__((address_space(3)))

static __device__ __forceinline__ void async_ld4(const float* g, float* l) {
    __builtin_amdgcn_global_load_lds((const GLOBAL_AS void*)g, (LDS_AS void*)l,
                                     4, 0, 0);
}

template <int TPB_, int CIN, int G, int PDT, int PHT, int PWT>
__global__ __launch_bounds__(TPB_, 2) void spline_block_kernel(
    const float* __restrict__ x,    // [N, CIN, D, H, W]
    const float* __restrict__ cw,   // [Cout, CIN, 27]
    const float* __restrict__ cb,   // [Cout]
    const float* __restrict__ knots,// [10]
    const float* __restrict__ sw,   // [Cout, 10]
    const float* __restrict__ w1,   // [Cout]
    const float* __restrict__ w2,   // [Cout]
    const float* __restrict__ g,    // [Cout]
    const float* __restrict__ beta, // [Cout]
    float* __restrict__ out,        // [N, Cout, PD, PH, PW]
    int N, int Cout, int D, int H, int W,
    int ntiles, int nthw, int ntw)
{
    constexpr int ID    = 2 * PDT + 2;
    constexpr int IH    = 2 * PHT + 2;
    constexpr int IW    = 2 * PWT + 2;
    constexpr int PITCH = 20;                 // even; row step 40 dwords = 8 mod 32 banks
    static_assert(IW <= PITCH, "tile width fits pitch");
    constexpr int PHYS  = ID * IH * PITCH;
    constexpr int NST   = (PHYS + TPB_ - 1) / TPB_;
    constexpr int BUFS  = (CIN > 1) ? 2 : 1;
    static_assert(NST <= 32, "mask fits u32");
    static_assert(PDT * PHT * PWT == TPB_, "one thread per pooled voxel");

    __shared__ float tile[BUFS][PHYS];
    __shared__ float wlds[CIN * G * 28];      // [ci*G+gg][27 pad 28], 16B rows

    const int PD = D >> 1, PH = H >> 1, PW = W >> 1;
    const int groups = Cout / G;
    const int tid = threadIdx.x;
    const int wbase = tid & ~63;

    const int bx      = blockIdx.x;
    const int tile_id = bx % ntiles;
    const int t1      = bx / ntiles;
    const int grp     = t1 % groups;
    const int n       = t1 / groups;
    const int c0      = grp * G;

    const int td  = tile_id / nthw;
    const int rem = tile_id % nthw;
    const int th_ = rem / ntw;
    const int tw_ = rem % ntw;

    // ---- one-time: zero tile buffers (borders stay 0 forever) + stage weights
    for (int i = tid; i < BUFS * PHYS; i += TPB_)
        (&tile[0][0])[i] = 0.0f;
    for (int i = tid; i < CIN * G * 27; i += TPB_) {
        const int t  = i % 27;
        const int cg = i / 27;
        const int gg = cg % G;
        const int ci = cg / G;
        wlds[cg * 28 + t] = cw[((c0 + gg) * CIN + ci) * 27 + t];
    }

    // thread's pooled voxel within the tile (pdl uniform per wave)
    const int pwl = tid % PWT;
    const int phl = (tid / PWT) % PHT;
    const int pdl = tid / (PWT * PHT);

    const int pd0 = td * PDT, ph0 = th_ * PHT, pw0 = tw_ * PWT;
    const int d0 = 2 * pd0 - 1, h0 = 2 * ph0 - 1, w0 = 2 * pw0 - 1;

    // staging offsets + validity mask (same for every cin; offsets into one channel)
    int offg[NST];
    unsigned vmask = 0;
#pragma unroll
    for (int k = 0; k < NST; k++) {
        const int p   = tid + TPB_ * k;
        const int wx  = p % PITCH;
        const int row = p / PITCH;
        const int hy  = row % IH;
        const int dz  = row / IH;
        const int dd = d0 + dz, hh = h0 + hy, ww = w0 + wx;
        const bool ok = (p < PHYS) & (wx < IW) &
                        ((unsigned)dd < (unsigned)D) &
                        ((unsigned)hh < (unsigned)H) &
                        ((unsigned)ww < (unsigned)W);
        offg[k] = ok ? (dd * H + hh) * W + ww : 0;
        vmask |= (unsigned)ok << k;
    }

    const size_t chstride = (size_t)D * H * W;
    const float* xn = x + (size_t)n * CIN * chstride;

    float acc[G][8];
#pragma unroll
    for (int gg = 0; gg < G; gg++) {
        const float bias = cb[c0 + gg];
#pragma unroll
        for (int i = 0; i < 8; i++) acc[gg][i] = bias;
    }

    __syncthreads();   // zeros + weights visible before DMA writes land

    // stage cin 0 into buf 0 (async DMA; drained by next barrier)
    {
        const float* xc = xn;
#pragma unroll
        for (int k = 0; k < NST; k++)
            if ((vmask >> k) & 1)
                async_ld4(xc + offg[k], &tile[0][TPB_ * k + wbase]);
    }
    __syncthreads();

    int cur = 0;
#pragma unroll 1
    for (int ci = 0; ci < CIN; ci++) {
        // prefetch next cin's slab into the other buffer (async)
        if (ci + 1 < CIN) {
            const float* xc = xn + (size_t)(ci + 1) * chstride;
#pragma unroll
            for (int k = 0; k < NST; k++)
                if ((vmask >> k) & 1)
                    async_ld4(xc + offg[k], &tile[cur ^ 1][TPB_ * k + wbase]);
        }

        // load this thread's 4x4x4 window from LDS (branch-free, float2 reads)
        const float* tb = &tile[cur][0];
        float r[64];
#pragma unroll
        for (int dz = 0; dz < 4; dz++)
#pragma unroll
        for (int dy = 0; dy < 4; dy++) {
            const int base = ((2 * pdl + dz) * IH + (2 * phl + dy)) * PITCH + 2 * pwl;
            const float2 v0 = *(const float2*)(tb + base);
            const float2 v1 = *(const float2*)(tb + base + 2);
            r[(dz * 4 + dy) * 4 + 0] = v0.x;
            r[(dz * 4 + dy) * 4 + 1] = v0.y;
            r[(dz * 4 + dy) * 4 + 2] = v1.x;
            r[(dz * 4 + dy) * 4 + 3] = v1.y;
        }

#pragma unroll
        for (int gg = 0; gg < G; gg++) {
            const float4* w4p = (const float4*)&wlds[(ci * G + gg) * 28];
#pragma unroll
            for (int ch = 0; ch < 7; ch++) {
                const float4 wv = w4p[ch];
#pragma unroll
                for (int j = 0; j < 4; j++) {
                    const int tap = ch * 4 + j;
                    if (tap < 27) {
                        const float wvj = (j == 0) ? wv.x : (j == 1) ? wv.y
                                        : (j == 2) ? wv.z : wv.w;
                        const int kd = tap / 9, kh = (tap % 9) / 3, kw = tap % 3;
#pragma unroll
                        for (int od = 0; od < 2; od++)
#pragma unroll
                        for (int oh = 0; oh < 2; oh++)
#pragma unroll
                        for (int ow = 0; ow < 2; ow++)
                            acc[gg][(od * 2 + oh) * 2 + ow] =
                                fmaf(wvj,
                                     r[((od + kd) * 4 + (oh + kh)) * 4 + (ow + kw)],
                                     acc[gg][(od * 2 + oh) * 2 + ow]);
                    }
                }
            }
        }

        if (ci + 1 < CIN) {
            __syncthreads();   // drain prefetch DMA; all reads of cur done
            cur ^= 1;
        }
    }

    // ---- spline + SiLU + BN affine + maxpool epilogue
    float kn[10];
#pragma unroll
    for (int k = 0; k < 10; k++) kn[k] = knots[k];

    const int pdg = pd0 + pdl, phg = ph0 + phl, pwg = pw0 + pwl;
#pragma unroll
    for (int gg = 0; gg < G; gg++) {
        const int c = c0 + gg;
        float sc[10];
#pragma unroll
        for (int k = 0; k < 10; k++) sc[k] = sw[c * 10 + k];
        const float W1 = w1[c], W2 = w2[c];
        const float scale = g[c] * rsqrtf(1.0f + 1e-5f);
        const float bb = beta[c];

        float m = -INFINITY;
#pragma unroll
        for (int i = 0; i < 8; i++) {
            const float y = acc[gg][i];
            float sp = 0.0f;
#pragma unroll
            for (int k = 0; k < 10; k++) {
                const float tt = fmaxf(y - kn[k], 0.0f);
                sp = fmaf(tt * tt * tt, sc[k], sp);
            }
            const float silu = y / (1.0f + __expf(-y));
            const float o = fmaf(W1 * sp + W2 * silu, scale, bb);
            m = fmaxf(m, o);
        }
        out[((size_t)(n * Cout + c) * PD + pdg) * PH * PW + phg * PW + pwg] = m;
    }
}

// Global average pool: one wave per (n,c); S = spatial size
__global__ __launch_bounds__(64) void mean_kernel(
    const float* __restrict__ h, float* __restrict__ out, int S)
{
    const int nc = blockIdx.x;
    const int lane = threadIdx.x;
    const float* p = h + (size_t)nc * S;
    float s = 0.0f;
    for (int i = lane; i < S; i += 64) s += p[i];
#pragma unroll
    for (int off = 32; off > 0; off >>= 1) s += __shfl_down(s, off, 64);
    if (lane == 0) out[nc] = s / (float)S;
}

// fc1(128->256)+ReLU then fc2(256->2), batch 2. One block of 256 threads.
__global__ __launch_bounds__(256) void fc_kernel(
    const float* __restrict__ pooled,
    const float* __restrict__ w1, const float* __restrict__ b1,
    const float* __restrict__ w2, const float* __restrict__ b2,
    float* __restrict__ out)
{
    __shared__ float hbuf[2][256];
    const int j = threadIdx.x;
#pragma unroll
    for (int nn = 0; nn < 2; nn++) {
        float s = b1[j];
        for (int k = 0; k < 128; k++)
            s = fmaf(pooled[nn * 128 + k], w1[j * 128 + k], s);
        hbuf[nn][j] = fmaxf(s, 0.0f);
    }
    __syncthreads();
    const int wid = j >> 6, lane = j & 63;
    const int nn = wid >> 1, oo = wid & 1;
    float s = 0.0f;
    for (int k = lane; k < 256; k += 64) s += hbuf[nn][k] * w2[oo * 256 + k];
#pragma unroll
    for (int off = 32; off > 0; off >>= 1) s += __shfl_down(s, off, 64);
    if (lane == 0) out[nn * 2 + oo] = s + b2[oo];
}

extern "C" void kernel_launch(void* const* d_in, const int* in_sizes, int n_in,
                              void* d_out, int out_size, void* d_ws, size_t ws_size,
                              hipStream_t stream) {
    const float* x      = (const float*)d_in[0];
    const float* c1_w   = (const float*)d_in[1];
    const float* c1_b   = (const float*)d_in[2];
    const float* c1_kn  = (const float*)d_in[3];
    const float* c1_sw  = (const float*)d_in[4];
    const float* c1_w1  = (const float*)d_in[5];
    const float* c1_w2  = (const float*)d_in[6];
    const float* bn1_g  = (const float*)d_in[7];
    const float* bn1_b  = (const float*)d_in[8];
    const float* c2_w   = (const float*)d_in[9];
    const float* c2_b   = (const float*)d_in[10];
    const float* c2_kn  = (const float*)d_in[11];
    const float* c2_sw  = (const float*)d_in[12];
    const float* c2_w1  = (const float*)d_in[13];
    const float* c2_w2  = (const float*)d_in[14];
    const float* bn2_g  = (const float*)d_in[15];
    const float* bn2_b  = (const float*)d_in[16];
    const float* c3_w   = (const float*)d_in[17];
    const float* c3_b   = (const float*)d_in[18];
    const float* c3_kn  = (const float*)d_in[19];
    const float* c3_sw  = (const float*)d_in[20];
    const float* c3_w1  = (const float*)d_in[21];
    const float* c3_w2  = (const float*)d_in[22];
    const float* bn3_g  = (const float*)d_in[23];
    const float* bn3_b  = (const float*)d_in[24];
    const float* fc1_w  = (const float*)d_in[25];
    const float* fc1_b  = (const float*)d_in[26];
    const float* fc2_w  = (const float*)d_in[27];
    const float* fc2_b  = (const float*)d_in[28];

    float* ws = (float*)d_ws;
    float* h1     = ws;                  // 2*32*32^3 = 2097152 floats
    float* h2     = h1 + 2097152;        // 2*64*16^3 =  524288 floats
    float* h3     = h2 + 524288;         // 2*128*8^3 =  131072 floats
    float* pooled = h3 + 131072;         // 2*128

    // L1: (2,1,64^3)->(2,32,32^3). G=4, tile 4x8x8 -> ntiles=8*4*4=128.
    // grid = 2 * (32/4) * 128 = 2048 blocks.
    spline_block_kernel<256, 1, 4, 4, 8, 8><<<dim3(2048), dim3(256), 0, stream>>>(
        x, c1_w, c1_b, c1_kn, c1_sw, c1_w1, c1_w2, bn1_g, bn1_b, h1,
        2, 32, 64, 64, 64, 128, 16, 4);
    // L2: (2,32,32^3)->(2,64,16^3). G=4, tile 4x8x8 -> ntiles=4*2*2=16.
    // grid = 2 * (64/4) * 16 = 512 blocks.
    spline_block_kernel<256, 32, 4, 4, 8, 8><<<dim3(512), dim3(256), 0, stream>>>(
        h1, c2_w, c2_b, c2_kn, c2_sw, c2_w1, c2_w2, bn2_g, bn2_b, h2,
        2, 64, 32, 32, 32, 16, 4, 2);
    // L3: (2,64,16^3)->(2,128,8^3). G=4, tile 2x8x8 (TPB=128) -> ntiles=4.
    // grid = 2 * (128/4) * 4 = 256 blocks.
    spline_block_kernel<128, 64, 4, 2, 8, 8><<<dim3(256), dim3(128), 0, stream>>>(
        h2, c3_w, c3_b, c3_kn, c3_sw, c3_w1, c3_w2, bn3_g, bn3_b, h3,
        2, 128, 16, 16, 16, 4, 1, 1);
    // Global mean pool: 256 (n,c) pairs, 512 voxels each
    mean_kernel<<<dim3(256), dim3(64), 0, stream>>>(h3, pooled, 512);
    // FC head
    fc_kernel<<<dim3(1), dim3(256), 0, stream>>>(pooled, fc1_w, fc1_b, fc2_w, fc2_b,
                                                 (float*)d_out);
}